// Round 1
// 180.974 us; speedup vs baseline: 1.0152x; 1.0152x over previous
//
#include <hip/hip_runtime.h>
#include <stdint.h>

#define B_   4
#define N_   4096
#define DIM_ 512
#define H_   8
#define DH_  64
#define E3_  1536
#define M_   (B_*N_)   // 16384

typedef __attribute__((ext_vector_type(8))) __bf16 bf16x8;
typedef __attribute__((ext_vector_type(8))) unsigned short ushort8;
typedef __attribute__((ext_vector_type(4))) float f32x4;

__device__ inline float bf2f(unsigned short u){ return __uint_as_float(((unsigned)u)<<16); }
__device__ inline unsigned short f2bf(float f){
  unsigned u = __float_as_uint(f);
  u += 0x7FFFu + ((u>>16)&1u);   // RNE
  return (unsigned short)(u>>16);
}

// async global->LDS, 16B per lane; lds dest = wave-uniform base + lane*16
__device__ inline void gld_lds16(const void* g, void* l){
  __builtin_amdgcn_global_load_lds(
      (const __attribute__((address_space(1))) void*)g,
      (__attribute__((address_space(3))) void*)l, 16, 0, 0);
}

// ---------------- format detection ----------------
// flags[0]: x fp32?  flags[1]: W/bias fp32?  flags[2]: mask 0=i32,1=f32,2=bf16,3=u8
__global__ void detect_fmt(const unsigned int* __restrict__ xw,
                           const unsigned int* __restrict__ ww,
                           const unsigned int* __restrict__ mw,
                           int* __restrict__ flags)
{
  __shared__ int cnt[2];
  __shared__ int ok[3];
  if (threadIdx.x < 2) cnt[threadIdx.x] = 0;
  if (threadIdx.x < 3) ok[threadIdx.x] = 1;
  __syncthreads();
  int hx = 0, hw = 0;
  for (int i = threadIdx.x; i < 1024; i += 256) {
    if (((xw[i] >> 7) & 0xFFu) > 140u) hx++;
    if (((ww[i] >> 7) & 0xFFu) > 140u) hw++;
  }
  int okInt = 1, okF32 = 1, okBf = 1;
  for (int i = threadIdx.x; i < 4096; i += 256) {
    unsigned w = mw[i];
    if (w > 1u) okInt = 0;
    if (w != 0u && w != 0x3F800000u) okF32 = 0;
    unsigned short a = (unsigned short)(w & 0xFFFFu), b = (unsigned short)(w >> 16);
    if (!((a == 0 || a == 0x3F80u) && (b == 0 || b == 0x3F80u))) okBf = 0;
  }
  atomicAdd(&cnt[0], hx);
  atomicAdd(&cnt[1], hw);
  if (!okInt) atomicAnd(&ok[0], 0);
  if (!okF32) atomicAnd(&ok[1], 0);
  if (!okBf)  atomicAnd(&ok[2], 0);
  __syncthreads();
  if (threadIdx.x == 0) {
    flags[0] = cnt[0] > 64 ? 1 : 0;
    flags[1] = cnt[1] > 64 ? 1 : 0;
    flags[2] = ok[0] ? 0 : (ok[1] ? 1 : (ok[2] ? 2 : 3));
  }
}

__device__ inline bool mask_at(const void* m, int flag, int idx){
  if (flag == 0) return ((const int*)m)[idx] != 0;
  if (flag == 1) return ((const float*)m)[idx] != 0.f;
  if (flag == 2) return ((const unsigned short*)m)[idx] != 0;
  return ((const unsigned char*)m)[idx] != 0;
}
__device__ inline float gread(const void* p, int f32, size_t i){
  return f32 ? ((const float*)p)[i] : bf2f(((const unsigned short*)p)[i]);
}

__device__ inline void unpack8(uint4 u, float* f){
  f[0] = bf2f((unsigned short)(u.x & 0xffff)); f[1] = bf2f((unsigned short)(u.x >> 16));
  f[2] = bf2f((unsigned short)(u.y & 0xffff)); f[3] = bf2f((unsigned short)(u.y >> 16));
  f[4] = bf2f((unsigned short)(u.z & 0xffff)); f[5] = bf2f((unsigned short)(u.z >> 16));
  f[6] = bf2f((unsigned short)(u.w & 0xffff)); f[7] = bf2f((unsigned short)(u.w >> 16));
}

// ---------------- pack x AND W into per-tile LDS images (fused, one launch) -------
// xq[((R*16 + kk)*512 + u)*8 + j], u = koct*128 + mlocal, covers
//   x[R*128+mlocal][kk*32 + koct*8 + j] as bf16.
// wq[((C*16 + kk)*512 + u)*8 + j], u = koct*128 + nlocal, covers
//   W[kk*32 + koct*8 + j][C*128 + nlocal] as bf16.
__global__ __launch_bounds__(256)
void pack_xw(const void* __restrict__ x, const void* __restrict__ w,
             unsigned short* __restrict__ xq, unsigned short* __restrict__ wq,
             const int* __restrict__ flags)
{
  if (blockIdx.x < 4096) {
    const int f = flags[0];
    const int g = blockIdx.x * 256 + threadIdx.x;   // 0..1048575
    const int R = g >> 13, rem = g & 8191;
    const int kk = rem >> 9, u = rem & 511;
    const int m = R * 128 + (u & 127);
    const int k0 = kk * 32 + (u >> 7) * 8;
    ushort8 v;
    if (f) {
      const float* xp = (const float*)x + (size_t)m * DIM_ + k0;
      float4 a = *(const float4*)xp, b = *(const float4*)(xp + 4);
      v[0]=f2bf(a.x); v[1]=f2bf(a.y); v[2]=f2bf(a.z); v[3]=f2bf(a.w);
      v[4]=f2bf(b.x); v[5]=f2bf(b.y); v[6]=f2bf(b.z); v[7]=f2bf(b.w);
    } else {
      v = *(const ushort8*)((const unsigned short*)x + (size_t)m * DIM_ + k0);
    }
    *(ushort8*)&xq[(size_t)g * 8] = v;
  } else {
    const int f = flags[1];
    const int g = (blockIdx.x - 4096) * 256 + threadIdx.x;   // 0..98303
    const int C = g >> 13, rem = g & 8191;
    const int kk = rem >> 9, u = rem & 511;
    const int n = C * 128 + (u & 127);
    const int k0 = kk * 32 + (u >> 7) * 8;
    ushort8 v;
    #pragma unroll
    for (int j = 0; j < 8; ++j) v[j] = f2bf(gread(w, f, (size_t)(k0 + j) * E3_ + n));
    *(ushort8*)&wq[(size_t)g * 8] = v;
  }
}

// ---------------- QKV GEMM: 128x128 tile, BK=64, dbuf LDS, 8 waves --------------
// T3-minimum pipeline: per K-tile {issue STAGE(next) -> ds_read+MFMA(cur) ->
// one __syncthreads (== vmcnt(0)+barrier)}. Stage overlaps MFMA of current tile.
// 8 waves = 2(M) x 4(N), per-wave out 64x32, acc[4][2]; 2 blocks/CU (64 KiB LDS).
__global__ __launch_bounds__(512, 4)
void qkv_gemm_fused(const unsigned short* __restrict__ xq,
                    const unsigned short* __restrict__ wq,
                    const void* __restrict__ bias, const void* __restrict__ mask,
                    const int* __restrict__ flags,
                    unsigned short* __restrict__ qb,
                    unsigned short* __restrict__ ekg,
                    unsigned short* __restrict__ vmg)
{
  const int wf = flags[1], mf = flags[2];
  __shared__ alignas(16) unsigned short As[2][8192];  // [buf][kc*512 + koct*128 + row]*8
  __shared__ alignas(16) unsigned short Bs[2][8192];
  const int t = threadIdx.x;
  const int lane = t & 63, wv = t >> 6;               // 8 waves
  const int quad = lane >> 4, l15 = lane & 15;
  const int m0 = blockIdx.y * 128, n0 = blockIdx.x * 128;
  const int mw = (wv & 1) * 64;                        // M-half of this wave
  const int nw = (wv >> 1) * 32;                       // N-quarter of this wave

  f32x4 acc[4][2];
  #pragma unroll
  for (int i = 0; i < 4; ++i)
    #pragma unroll
    for (int j = 0; j < 2; ++j) acc[i][j] = (f32x4){0.f,0.f,0.f,0.f};

  const unsigned short* aim0 = xq + ((size_t)(blockIdx.y * 16) * 512) * 8;
  const unsigned short* bim0 = wq + ((size_t)(blockIdx.x * 16) * 512) * 8;

  auto stage = [&](int kt, int bb) {
    // two consecutive kk-images (kk=2kt, 2kt+1) are contiguous in global memory
    const unsigned short* aim = aim0 + (size_t)kt * (2 * 512 * 8);
    const unsigned short* bim = bim0 + (size_t)kt * (2 * 512 * 8);
    #pragma unroll
    for (int h2 = 0; h2 < 2; ++h2) {
      const int u0 = h2 * 512 + wv * 64;   // wave-uniform LDS base; lane-contig global
      gld_lds16(aim + (size_t)(u0 + lane) * 8, &As[bb][u0 * 8]);
      gld_lds16(bim + (size_t)(u0 + lane) * 8, &Bs[bb][u0 * 8]);
    }
  };

  stage(0, 0);
  __syncthreads();                         // drain prologue stage
  int cur = 0;
  for (int kt = 0; kt < 8; ++kt) {
    if (kt < 7) stage(kt + 1, cur ^ 1);    // issue BEFORE compute; drains at barrier below
    #pragma unroll
    for (int kc = 0; kc < 2; ++kc) {
      ushort8 af[4], bfr[2];
      #pragma unroll
      for (int i = 0; i < 4; ++i)
        af[i] = *(const ushort8*)&As[cur][(kc * 512 + quad * 128 + mw + i * 16 + l15) * 8];
      #pragma unroll
      for (int j = 0; j < 2; ++j)
        bfr[j] = *(const ushort8*)&Bs[cur][(kc * 512 + quad * 128 + nw + j * 16 + l15) * 8];
      #pragma unroll
      for (int i = 0; i < 4; ++i)
        #pragma unroll
        for (int j = 0; j < 2; ++j)
          acc[i][j] = __builtin_amdgcn_mfma_f32_16x16x32_bf16(
              __builtin_bit_cast(bf16x8, af[i]), __builtin_bit_cast(bf16x8, bfr[j]),
              acc[i][j], 0, 0, 0);
    }
    __syncthreads();                       // one vmcnt(0)+barrier per K-tile
    cur ^= 1;
  }

  const int mode = blockIdx.x >> 2;        // 0=q, 1=k, 2=v (block-uniform)
  if (mode == 0) {
    #pragma unroll
    for (int j = 0; j < 2; ++j) {
      int col = n0 + nw + j * 16 + l15;
      float bv = gread(bias, wf, col);
      #pragma unroll
      for (int i = 0; i < 4; ++i)
        #pragma unroll
        for (int r = 0; r < 4; ++r) {
          int row = m0 + mw + i * 16 + quad * 4 + r;
          qb[(size_t)row * 512 + col] = f2bf(acc[i][j][r] + bv);
        }
    }
  } else {
    unsigned short* dstbuf = (mode == 1) ? ekg : vmg;
    float bj[2]; int hj[2], dj[2];
    #pragma unroll
    for (int j = 0; j < 2; ++j) {
      int col = n0 + nw + j * 16 + l15;
      bj[j] = gread(bias, wf, col);
      int rel = col - mode * 512;
      hj[j] = rel >> 6; dj[j] = rel & 63;
    }
    #pragma unroll
    for (int i = 0; i < 4; ++i)
      #pragma unroll
      for (int r = 0; r < 4; ++r) {
        int row = m0 + mw + i * 16 + quad * 4 + r;
        bool mk = mask_at(mask, mf, row);
        int bb2 = row >> 12, nn = row & 4095;
        size_t base = (size_t)(nn >> 3) * 512 + (nn & 7);
        #pragma unroll
        for (int j = 0; j < 2; ++j) {
          float val = acc[i][j][r] + bj[j];
          val = (mode == 1) ? (mk ? __expf(val) : 0.f) : (mk ? val : 0.f);
          dstbuf[(size_t)(bb2 * 8 + hj[j]) * 262144 + base + (size_t)dj[j] * 8] = f2bf(val);
        }
      }
  }
}

// ---------------- kv GEMM: per-block partial over 256 tokens, 512 blocks ----------
__global__ __launch_bounds__(256)
void kv_gemm(const unsigned short* __restrict__ ekg,
             const unsigned short* __restrict__ vmg,
             float* __restrict__ kvpart, float* __restrict__ denpart)
{
  const int sc = blockIdx.x;   // 0..15 (256-token chunk)
  const int bh = blockIdx.y;   // 0..31
  const int t  = threadIdx.x;
  const int lane = t & 63, wv = t >> 6;
  const int quad = lane >> 4, l15 = lane & 15;
  __shared__ alignas(16) unsigned short ekS[16384];  // [ktl 0..31][d 0..63][8]
  __shared__ alignas(16) unsigned short vmS[16384];

  f32x4 acc[4];
  #pragma unroll
  for (int j = 0; j < 4; ++j) acc[j] = (f32x4){0.f,0.f,0.f,0.f};
  float dsum = 0.f;
  const int dden = t & 63, g0 = (t >> 6) * 8;
  const size_t gbase = (size_t)bh * 262144 + (size_t)sc * 16384;

  #pragma unroll
  for (int i = 0; i < 8; ++i) {
    int u0 = i * 256 + wv * 64;          // wave-uniform LDS base, lane-contig global
    gld_lds16(&ekg[gbase + (size_t)(u0 + lane) * 8], &ekS[u0 * 8]);
    gld_lds16(&vmg[gbase + (size_t)(u0 + lane) * 8], &vmS[u0 * 8]);
  }
  __syncthreads();
  {  // denom partial: sum ek over staged tokens, per d
    #pragma unroll
    for (int kt = 0; kt < 8; ++kt) {
      ushort8 v = *(const ushort8*)&ekS[((g0 + kt) * 64 + dden) * 8];
      #pragma unroll
      for (int j = 0; j < 8; ++j) dsum += bf2f(v[j]);
    }
  }
  #pragma unroll 2
  for (int ks = 0; ks < 8; ++ks) {
    ushort8 af = *(const ushort8*)&ekS[((ks * 4 + quad) * 64 + wv * 16 + l15) * 8];
    #pragma unroll
    for (int jt = 0; jt < 4; ++jt) {
      ushort8 bf8 = *(const ushort8*)&vmS[((ks * 4 + quad) * 64 + jt * 16 + l15) * 8];
      acc[jt] = __builtin_amdgcn_mfma_f32_16x16x32_bf16(
          __builtin_bit_cast(bf16x8, af), __builtin_bit_cast(bf16x8, bf8),
          acc[jt], 0, 0, 0);
    }
  }
  float* kvp = kvpart + (size_t)(sc * 32 + bh) * 4096;
  #pragma unroll
  for (int jt = 0; jt < 4; ++jt)
    #pragma unroll
    for (int r = 0; r < 4; ++r)
      kvp[(wv * 16 + quad * 4 + r) * 64 + jt * 16 + l15] = acc[jt][r];
  __syncthreads();
  float* red = (float*)ekS;
  red[t] = dsum;
  __syncthreads();
  if (t < 64)
    denpart[(sc * 32 + bh) * 64 + t] = red[t] + red[t + 64] + red[t + 128] + red[t + 192];
}

// ---------------- reduce partials -> normalized kv in bf16 B-frag layout ----------
// grid (32 bh, 4 d-quarters); kvnb[bh] unit (doct,e): kvn[doct*8+j][e] at ((doct*64+e)*8+j)
__global__ __launch_bounds__(256)
void kv_reduce(const float* __restrict__ kvpart, const float* __restrict__ denpart,
               unsigned short* __restrict__ kvnb)
{
  const int bh = blockIdx.x;     // 0..31
  const int qd = blockIdx.y;     // 0..3: d-range qd*16..+15
  const int t  = threadIdx.x;
  __shared__ float den[16];
  if (t < 16) {
    float s = 0.f;
    #pragma unroll
    for (int c = 0; c < 16; ++c) s += denpart[(c * 32 + bh) * 64 + qd * 16 + t];
    den[t] = s;
  }
  __syncthreads();
  const int dl = t >> 4, e0 = (t & 15) * 4;
  const int d = qd * 16 + dl;
  float sx = 0.f, sy = 0.f, sz = 0.f, sw = 0.f;
  #pragma unroll
  for (int c = 0; c < 16; ++c) {
    const float4 v = *(const float4*)&kvpart[(size_t)(c * 32 + bh) * 4096 + d * 64 + e0];
    sx += v.x; sy += v.y; sz += v.z; sw += v.w;
  }
  const float inv = 1.f / den[dl];
  const float sv[4] = {sx, sy, sz, sw};
  #pragma unroll
  for (int j = 0; j < 4; ++j) {
    int e = e0 + j;
    kvnb[(size_t)bh * 4096 + ((size_t)(d >> 3) * 64 + e) * 8 + (d & 7)] = f2bf(sv[j] * inv);
  }
}

// ---------------- output: in-register q-softmax in MFMA A-frag layout -------------
// A-frag: row = l15 = token, k = quad*8+j (+32 for 2nd chunk) = d. Row-reduce =
// 16 in-lane values + shfl_xor(16)+shfl_xor(32). No LDS round-trip, no barriers
// in the main loop; waves fully autonomous after one kvS load.
__global__ __launch_bounds__(256)
void out_pass(const unsigned short* __restrict__ qb,
              const unsigned short* __restrict__ kvnb,
              float* __restrict__ out)
{
  const int chunk = blockIdx.x, bh = blockIdx.y;
  const int b = bh >> 3, h = bh & 7;
  const int t = threadIdx.x;
  const int lane = t & 63, wv = t >> 6;
  const int quad = lane >> 4, l15 = lane & 15;
  __shared__ alignas(16) unsigned short kvS[4096];   // [(doct*64+e)*8+j]
  #pragma unroll
  for (int i = 0; i < 2; ++i)
    *(ushort8*)&kvS[(t + i * 256) * 8] =
        *(const ushort8*)&kvnb[(size_t)bh * 4096 + (size_t)(t + i * 256) * 8];
  __syncthreads();

  for (int g = 0; g < 4; ++g) {
    const int tok0 = chunk * 256 + wv * 64 + g * 16;
    const size_t qoff = (size_t)(b * N_ + tok0 + l15) * 512 + h * DH_ + quad * 8;
    uint4 qa = *(const uint4*)(qb + qoff);        // d = quad*8 .. +7
    uint4 qc = *(const uint4*)(qb + qoff + 32);   // d = 32+quad*8 .. +7
    float qf[16];
    unpack8(qa, qf); unpack8(qc, qf + 8);
    float mx = qf[0];
    #pragma unroll
    for (int jj = 1; jj < 16; ++jj) mx = fmaxf(mx, qf[jj]);
    mx = fmaxf(mx, __shfl_xor(mx, 16));
    mx = fmaxf(mx, __shfl_xor(mx, 32));
    float s = 0.f;
    #pragma unroll
    for (int jj = 0; jj < 16; ++jj) { qf[jj] = __expf(qf[jj] - mx); s += qf[jj]; }
    s += __shfl_xor(s, 16);
    s += __shfl_xor(s, 32);
    const float inv = 1.f / s;
    ushort8 af0, af1;
    #pragma unroll
    for (int jj = 0; jj < 8; ++jj) {
      af0[jj] = f2bf(qf[jj] * inv);
      af1[jj] = f2bf(qf[8 + jj] * inv);
    }
    f32x4 oa[4];
    #pragma unroll
    for (int jt = 0; jt < 4; ++jt) oa[jt] = (f32x4){0.f,0.f,0.f,0.f};
    #pragma unroll
    for (int jt = 0; jt < 4; ++jt) {
      ushort8 b0 = *(const ushort8*)&kvS[((0 + quad) * 64 + jt * 16 + l15) * 8];
      ushort8 b1 = *(const ushort8*)&kvS[((4 + quad) * 64 + jt * 16 + l15) * 8];
      oa[jt] = __builtin_amdgcn_mfma_f32_16x16x32_bf16(
          __builtin_bit_cast(bf16x8, af0), __builtin_bit_cast(bf16x8, b0), oa[jt], 0, 0, 0);
      oa[jt] = __builtin_amdgcn_mfma_f32_16x16x32_bf16(
          __builtin_bit_cast(bf16x8, af1), __builtin_bit_cast(bf16x8, b1), oa[jt], 0, 0, 0);
    }
    const size_t ob = (size_t)(b * N_ + tok0 + quad * 4) * 512 + h * DH_;
    #pragma unroll
    for (int jt = 0; jt < 4; ++jt)
      #pragma unroll
      for (int r = 0; r < 4; ++r)
        out[ob + (size_t)r * 512 + jt * 16 + l15] = oa[jt][r];
  }
}

// ================= round-5 fused fallback (only if ws too small) =================
__device__ inline void stage_x_f(float (*xa)[516], const void* x, int xf, int brow0, int t)
{
  if (xf) {
    const float* xp = (const float*)x;
    #pragma unroll
    for (int s = 0; s < 8; ++s) {
      int row = (t >> 7) + 2 * s, col = (t & 127) * 4;
      *(float4*)&xa[row][col] = *(const float4*)(xp + ((size_t)(brow0 + row)) * DIM_ + col);
    }
  } else {
    const unsigned short* xp = (const unsigned short*)x;
    #pragma unroll
    for (int s = 0; s < 8; ++s) {
      int row = (t >> 7) + 2 * s, col = (t & 127) * 4;
      const unsigned short* pp = xp + ((size_t)(brow0 + row)) * DIM_ + col;
      #pragma unroll
      for (int j = 0; j < 4; ++j) xa[row][col + j] = bf2f(pp[j]);
    }
  }
}

__global__ __launch_bounds__(256)
void kv_pass_fused(const void* __restrict__ x, const void* __restrict__ w,
                   const void* __restrict__ bias, const void* __restrict__ mask,
                   const int* __restrict__ flags,
                   float* __restrict__ kvbuf, float* __restrict__ denom)
{
  const int chunk = blockIdx.x, bh = blockIdx.y;
  const int b = bh >> 3, h = bh & 7;
  const int t = threadIdx.x;
  const int xf = flags[0], wf = flags[1], mf = flags[2];
  __shared__ float xa[16][516];
  __shared__ float Wb[64][130];
  float* ekb = &Wb[0][0];
  float* vvb = &Wb[0][0] + 16 * 65;
  const int tok = t >> 4, d0 = (t & 15) * 4;
  const int down = t >> 2, e0 = (t & 3) * 16;
  float acc[16];
  #pragma unroll
  for (int i = 0; i < 16; ++i) acc[i] = 0.f;
  float dsum = 0.f;
  for (int g = 0; g < 16; ++g) {
    const int n0 = chunk * 256 + g * 16;
    __syncthreads();
    stage_x_f(xa, x, xf, b * N_ + n0, t);
    float kreg[4] = {0,0,0,0}, vreg[4] = {0,0,0,0};
    for (int cc = 0; cc < 8; ++cc) {
      __syncthreads();
      {
        int c0 = (t >> 7) * 32, col = t & 127;
        int wc = (col < 64) ? (512 + h * DH_ + col) : (1024 + h * DH_ + (col - 64));
        #pragma unroll 8
        for (int j = 0; j < 32; ++j)
          Wb[c0 + j][col] = gread(w, wf, (size_t)(cc * 64 + c0 + j) * E3_ + wc);
      }
      __syncthreads();
      #pragma unroll 4
      for (int c = 0; c < 64; ++c) {
        float xv = xa[tok][cc * 64 + c];
        #pragma unroll
        for (int j = 0; j < 4; ++j) {
          kreg[j] += xv * Wb[c][d0 + j];
          vreg[j] += xv * Wb[c][64 + d0 + j];
        }
      }
    }
    bool mk = mask_at(mask, mf, b * N_ + n0 + tok);
    __syncthreads();
    #pragma unroll
    for (int j = 0; j < 4; ++j) {
      float kvl = kreg[j] + gread(bias, wf, 512  + h * DH_ + d0 + j);
      float vvl = vreg[j] + gread(bias, wf, 1024 + h * DH_ + d0 + j);
      ekb[tok * 65 + d0 + j] = mk ? __expf(kvl) : 0.f;
      vvb[tok * 65 + d0 + j] = mk ? vvl : 0.f;
    }
    __syncthreads();
    #pragma unroll 4
    for (int nn = 0; nn < 16; ++nn) {
      float ekd = ekb[nn * 65 + down];
      if (e0 == 0) dsum += ekd;
      #pragma unroll
      for (int i = 0; i < 16; ++i) acc[i] += ekd * vvb[nn * 65 + e0 + i];
    }
  }
  float* kvp = kvbuf + (size_t)bh * 4096 + down * 64 + e0;
  #pragma unroll
  for (int i = 0; i < 16; ++i) atomicAdd(&kvp[i], acc[i]);
  if (e0 == 0) atomicAdd(&denom[bh * 64 + down], dsum);
}

__global__ __launch_bounds__(256)
void out_pass_fused(const void* __restrict__ x, const void* __restrict__ w,
                    const void* __restrict__ bias, const int* __restrict__ flags,
                    const float* __restrict__ kvbuf, const float* __restrict__ denom,
                    float* __restrict__ out)
{
  const int chunk = blockIdx.x, bh = blockIdx.y;
  const int b = bh >> 3, h = bh & 7;
  const int t = threadIdx.x;
  const int xf = flags[0], wf = flags[1];
  __shared__ float xa[16][516];
  __shared__ float Wq[64][66];
  __shared__ float kvn[64][68];
  float* qsm = &Wq[0][0];
  for (int i = t; i < 4096; i += 256) {
    int d = i >> 6, e = i & 63;
    kvn[d][e] = kvbuf[(size_t)bh * 4096 + i] / denom[bh * 64 + d];
  }
  const int tok = t >> 4, p = t & 15, d0 = p * 4;
  for (int g = 0; g < 16; ++g) {
    const int n0 = chunk * 256 + g * 16;
    __syncthreads();
    stage_x_f(xa, x, xf, b * N_ + n0, t);
    float qreg[4] = {0,0,0,0};
    for (int cc = 0; cc < 8; ++cc) {
      __syncthreads();
      {
        int col = t & 63, c0 = (t >> 6) * 16;
        #pragma unroll 8
        for (int j = 0; j < 16; ++j)
          Wq[c0 + j][col] = gread(w, wf, (size_t)(cc * 64 + c0 + j) * E3_ + h * DH_ + col);
      }
      __syncthreads();
      #pragma unroll 4
      for (int c = 0; c < 64; ++c) {
        float xv = xa[tok][cc * 64 + c];
        #pragma unroll
        for (int j = 0; j < 4; ++j) qreg[j] += xv * Wq[c][d0 + j];
      }
    }
    #pragma unroll
    for (int j = 0; j < 4; ++j) qreg[j] += gread(bias, wf, h * DH_ + d0 + j);
    float mx = fmaxf(fmaxf(qreg[0], qreg[1]), fmaxf(qreg[2], qreg[3]));
    #pragma unroll
    for (int o = 1; o < 16; o <<= 1) mx = fmaxf(mx, __shfl_xor(mx, o, 16));
    float s = 0.f;
    #pragma unroll
    for (int j = 0; j < 4; ++j) { qreg[j] = __expf(qreg[j] - mx); s += qreg[j]; }
    #pragma unroll
    for (int o = 1; o < 16; o <<= 1) s += __shfl_xor(s, o, 16);
    float inv = 1.f / s;
    __syncthreads();
    #pragma unroll
    for (int j = 0; j < 4; ++j) qsm[tok * 65 + d0 + j] = qreg[j] * inv;
    __syncthreads();
    {
      int e0 = p * 4;
      float ov[4] = {0,0,0,0};
      #pragma unroll 4
      for (int d = 0; d < 64; ++d) {
        float qd = qsm[tok * 65 + d];
        #pragma unroll
        for (int j = 0; j < 4; ++j) ov[j] += qd * kvn[d][e0 + j];
      }
      size_t ob = ((size_t)(b * N_ + n0 + tok)) * DIM_ + h * DH_ + e0;
      #pragma unroll
      for (int j = 0; j < 4; ++j) out[ob + j] = ov[j];
    }
  }
}

extern "C" void kernel_launch(void* const* d_in, const int* in_sizes, int n_in,
                              void* d_out, int out_size, void* d_ws, size_t ws_size,
                              hipStream_t stream)
{
  const void* x    = d_in[0];
  const void* mask = d_in[1];
  const void* w    = d_in[2];
  const void* bias = d_in[3];
  float* out = (float*)d_out;

  char* ws = (char*)d_ws;
  const size_t offFlg = 0;                                   // 4 KB slot
  const size_t offXq  = 4096;                                // 16.78 MB (dead after GEMM)
  const size_t offWq  = offXq + (size_t)M_ * DIM_ * 2;       // 1.57 MB
  const size_t offQ   = offWq + (size_t)E3_ * DIM_ * 2;      // 16.78 MB
  const size_t offEk  = offQ  + (size_t)M_ * DIM_ * 2;       // 16.78 MB
  const size_t offVm  = offEk + (size_t)M_ * DH_ * H_ * 2;   // 16.78 MB
  const size_t need   = offVm + (size_t)M_ * DH_ * H_ * 2;
  // aliased into dead xq region (after qkv_gemm_fused):
  const size_t offKvp = offXq;                               // 16*32*4096*4 = 8 MB
  const size_t offDnp = offXq + 8388608;                     // 16*32*64*4 = 128 KB
  const size_t offKvn = offXq + 8388608 + 131072;            // 256 KB

  int* flags = (int*)(ws + offFlg);
  detect_fmt<<<1, 256, 0, stream>>>((const unsigned int*)x, (const unsigned int*)w,
                                    (const unsigned int*)mask, flags);

  if (ws_size >= need) {
    unsigned short* xq  = (unsigned short*)(ws + offXq);
    unsigned short* wq  = (unsigned short*)(ws + offWq);
    unsigned short* qb  = (unsigned short*)(ws + offQ);
    unsigned short* ekg = (unsigned short*)(ws + offEk);
    unsigned short* vmg = (unsigned short*)(ws + offVm);
    float* kvpart = (float*)(ws + offKvp);
    float* denpart = (float*)(ws + offDnp);
    unsigned short* kvnb = (unsigned short*)(ws + offKvn);

    pack_xw<<<4480, 256, 0, stream>>>(x, w, xq, wq, flags);
    dim3 gg(E3_ / 128, M_ / 128);   // 12 x 128
    qkv_gemm_fused<<<gg, 512, 0, stream>>>(xq, wq, bias, mask, flags, qb, ekg, vmg);
    kv_gemm<<<dim3(16, 32), 256, 0, stream>>>(ekg, vmg, kvpart, denpart);
    kv_reduce<<<dim3(32, 4), 256, 0, stream>>>(kvpart, denpart, kvnb);
    out_pass<<<dim3(16, 32), 256, 0, stream>>>(qb, kvnb, out);
  } else {
    float* kvbuf = (float*)(ws + 4096);
    float* denom = (float*)(ws + 4096 + 32 * 4096 * 4);
    hipMemsetAsync(kvbuf, 0, 32 * 4096 * 4 + 32 * 64 * 4, stream);
    dim3 ga(16, 32);
    kv_pass_fused <<<ga, 256, 0, stream>>>(x, w, bias, mask, flags, kvbuf, denom);
    out_pass_fused<<<ga, 256, 0, stream>>>(x, w, bias, flags, kvbuf, denom, out);
  }
}

// Round 2
// 172.925 us; speedup vs baseline: 1.0625x; 1.0465x over previous
//
#include <hip/hip_runtime.h>
#include <stdint.h>

#define B_   4
#define N_   4096
#define DIM_ 512
#define H_   8
#define DH_  64
#define E3_  1536
#define M_   (B_*N_)   // 16384

typedef __attribute__((ext_vector_type(8))) __bf16 bf16x8;
typedef __attribute__((ext_vector_type(8))) unsigned short ushort8;
typedef __attribute__((ext_vector_type(4))) float f32x4;

__device__ inline float bf2f(unsigned short u){ return __uint_as_float(((unsigned)u)<<16); }
__device__ inline unsigned short f2bf(float f){
  unsigned u = __float_as_uint(f);
  u += 0x7FFFu + ((u>>16)&1u);   // RNE
  return (unsigned short)(u>>16);
}

// async global->LDS, 16B per lane; lds dest = wave-uniform base + lane*16
__device__ inline void gld_lds16(const void* g, void* l){
  __builtin_amdgcn_global_load_lds(
      (const __attribute__((address_space(1))) void*)g,
      (__attribute__((address_space(3))) void*)l, 16, 0, 0);
}

// ---------------- format detection ----------------
// flags[0]: x fp32?  flags[1]: W/bias fp32?  flags[2]: mask 0=i32,1=f32,2=bf16,3=u8
__global__ void detect_fmt(const unsigned int* __restrict__ xw,
                           const unsigned int* __restrict__ ww,
                           const unsigned int* __restrict__ mw,
                           int* __restrict__ flags)
{
  __shared__ int cnt[2];
  __shared__ int ok[3];
  if (threadIdx.x < 2) cnt[threadIdx.x] = 0;
  if (threadIdx.x < 3) ok[threadIdx.x] = 1;
  __syncthreads();
  int hx = 0, hw = 0;
  for (int i = threadIdx.x; i < 1024; i += 256) {
    if (((xw[i] >> 7) & 0xFFu) > 140u) hx++;
    if (((ww[i] >> 7) & 0xFFu) > 140u) hw++;
  }
  int okInt = 1, okF32 = 1, okBf = 1;
  for (int i = threadIdx.x; i < 4096; i += 256) {
    unsigned w = mw[i];
    if (w > 1u) okInt = 0;
    if (w != 0u && w != 0x3F800000u) okF32 = 0;
    unsigned short a = (unsigned short)(w & 0xFFFFu), b = (unsigned short)(w >> 16);
    if (!((a == 0 || a == 0x3F80u) && (b == 0 || b == 0x3F80u))) okBf = 0;
  }
  atomicAdd(&cnt[0], hx);
  atomicAdd(&cnt[1], hw);
  if (!okInt) atomicAnd(&ok[0], 0);
  if (!okF32) atomicAnd(&ok[1], 0);
  if (!okBf)  atomicAnd(&ok[2], 0);
  __syncthreads();
  if (threadIdx.x == 0) {
    flags[0] = cnt[0] > 64 ? 1 : 0;
    flags[1] = cnt[1] > 64 ? 1 : 0;
    flags[2] = ok[0] ? 0 : (ok[1] ? 1 : (ok[2] ? 2 : 3));
  }
}

__device__ inline bool mask_at(const void* m, int flag, int idx){
  if (flag == 0) return ((const int*)m)[idx] != 0;
  if (flag == 1) return ((const float*)m)[idx] != 0.f;
  if (flag == 2) return ((const unsigned short*)m)[idx] != 0;
  return ((const unsigned char*)m)[idx] != 0;
}
__device__ inline float gread(const void* p, int f32, size_t i){
  return f32 ? ((const float*)p)[i] : bf2f(((const unsigned short*)p)[i]);
}

__device__ inline void unpack8(uint4 u, float* f){
  f[0] = bf2f((unsigned short)(u.x & 0xffff)); f[1] = bf2f((unsigned short)(u.x >> 16));
  f[2] = bf2f((unsigned short)(u.y & 0xffff)); f[3] = bf2f((unsigned short)(u.y >> 16));
  f[4] = bf2f((unsigned short)(u.z & 0xffff)); f[5] = bf2f((unsigned short)(u.z >> 16));
  f[6] = bf2f((unsigned short)(u.w & 0xffff)); f[7] = bf2f((unsigned short)(u.w >> 16));
}

// ---------------- pack x AND W into per-tile LDS images (fused, one launch) -------
// xq[((R*16 + kk)*512 + u)*8 + j], u = koct*128 + mlocal, covers
//   x[R*128+mlocal][kk*32 + koct*8 + j] as bf16.
// wq[((C*16 + kk)*512 + u)*8 + j], u = koct*128 + nlocal, covers
//   W[kk*32 + koct*8 + j][C*128 + nlocal] as bf16.
__global__ __launch_bounds__(256)
void pack_xw(const void* __restrict__ x, const void* __restrict__ w,
             unsigned short* __restrict__ xq, unsigned short* __restrict__ wq,
             const int* __restrict__ flags)
{
  if (blockIdx.x < 4096) {
    const int f = flags[0];
    const int g = blockIdx.x * 256 + threadIdx.x;   // 0..1048575
    const int R = g >> 13, rem = g & 8191;
    const int kk = rem >> 9, u = rem & 511;
    const int m = R * 128 + (u & 127);
    const int k0 = kk * 32 + (u >> 7) * 8;
    ushort8 v;
    if (f) {
      const float* xp = (const float*)x + (size_t)m * DIM_ + k0;
      float4 a = *(const float4*)xp, b = *(const float4*)(xp + 4);
      v[0]=f2bf(a.x); v[1]=f2bf(a.y); v[2]=f2bf(a.z); v[3]=f2bf(a.w);
      v[4]=f2bf(b.x); v[5]=f2bf(b.y); v[6]=f2bf(b.z); v[7]=f2bf(b.w);
    } else {
      v = *(const ushort8*)((const unsigned short*)x + (size_t)m * DIM_ + k0);
    }
    *(ushort8*)&xq[(size_t)g * 8] = v;
  } else {
    const int f = flags[1];
    const int g = (blockIdx.x - 4096) * 256 + threadIdx.x;   // 0..98303
    const int C = g >> 13, rem = g & 8191;
    const int kk = rem >> 9, u = rem & 511;
    const int n = C * 128 + (u & 127);
    const int k0 = kk * 32 + (u >> 7) * 8;
    ushort8 v;
    #pragma unroll
    for (int j = 0; j < 8; ++j) v[j] = f2bf(gread(w, f, (size_t)(k0 + j) * E3_ + n));
    *(ushort8*)&wq[(size_t)g * 8] = v;
  }
}

// ---------------- QKV GEMM: 128x128 tile, 4-buffer depth-2 counted-vmcnt pipeline --
// T4 counted vmcnt: tile t's loads issued 2 iterations ahead (~400+ cy to land).
// Per tile: stage(t+2) -> s_waitcnt vmcnt(8) [t's 4 loads done; 8 newer in flight,
// NEVER drained to 0 in loop] -> raw s_barrier -> ds_read+MFMA. Buffer (t+2)&3 was
// last read at tile t-2, finished by all waves before barrier(t-1) => race-free.
// 4 waves, acc[4][4] (round-0 verified layout), XCD-bijective block swizzle.
__global__ __launch_bounds__(256, 2)
void qkv_gemm_fused(const unsigned short* __restrict__ xq,
                    const unsigned short* __restrict__ wq,
                    const void* __restrict__ bias, const void* __restrict__ mask,
                    const int* __restrict__ flags,
                    unsigned short* __restrict__ qb,
                    unsigned short* __restrict__ ekg,
                    unsigned short* __restrict__ vmg)
{
  const int wf = flags[1], mf = flags[2];
  __shared__ alignas(16) unsigned short As[4][4096];  // 4 bufs x 8KB (128x32 bf16)
  __shared__ alignas(16) unsigned short Bs[4][4096];
  const int t = threadIdx.x;
  const int lane = t & 63, wv = t >> 6;
  const int quad = lane >> 4, l15 = lane & 15;
  // XCD swizzle: co-locate the 12 col-blocks sharing one A-panel on one XCD.
  // nwg=1536, 1536%8==0 -> bijective: logical = (hw%8)*192 + hw/8.
  const int hwf = blockIdx.y * 12 + blockIdx.x;
  const int lf  = (hwf & 7) * 192 + (hwf >> 3);
  const int bx = lf % 12, by = lf / 12;
  const int m0 = by * 128, n0 = bx * 128;
  const int mw = (wv & 1) * 64, nw = (wv >> 1) * 64;

  f32x4 acc[4][4];
  #pragma unroll
  for (int i = 0; i < 4; ++i)
    #pragma unroll
    for (int j = 0; j < 4; ++j) acc[i][j] = (f32x4){0.f,0.f,0.f,0.f};

  const unsigned short* aim0 = xq + ((size_t)(by * 16) * 512) * 8;
  const unsigned short* bim0 = wq + ((size_t)(bx * 16) * 512) * 8;

  auto stage = [&](int kk, int bb) {
    const unsigned short* aim = aim0 + (size_t)kk * 4096;
    const unsigned short* bim = bim0 + (size_t)kk * 4096;
    #pragma unroll
    for (int s = 0; s < 2; ++s) {
      const int u0 = s * 256 + wv * 64;   // wave-uniform LDS base; lane-contig global
      gld_lds16(aim + (size_t)(u0 + lane) * 8, &As[bb][u0 * 8]);
      gld_lds16(bim + (size_t)(u0 + lane) * 8, &Bs[bb][u0 * 8]);
    }
  };

  stage(0, 0);
  stage(1, 1);
  #pragma unroll
  for (int kk = 0; kk < 16; ++kk) {
    const int bb = kk & 3;
    if (kk < 14) stage(kk + 2, (kk + 2) & 3);
    // counted wait: my tile-kk loads (4) done; tiles kk+1,kk+2 (8) stay in flight
    if (kk < 14)       asm volatile("s_waitcnt vmcnt(8)" ::: "memory");
    else if (kk == 14) asm volatile("s_waitcnt vmcnt(4)" ::: "memory");
    else               asm volatile("s_waitcnt vmcnt(0)" ::: "memory");
    __builtin_amdgcn_sched_barrier(0);
    __builtin_amdgcn_s_barrier();       // all waves' tile-kk loads resident
    __builtin_amdgcn_sched_barrier(0);
    ushort8 af[4], bfr[4];
    #pragma unroll
    for (int i = 0; i < 4; ++i) {
      af[i]  = *(const ushort8*)&As[bb][(quad * 128 + mw + i * 16 + l15) * 8];
      bfr[i] = *(const ushort8*)&Bs[bb][(quad * 128 + nw + i * 16 + l15) * 8];
    }
    #pragma unroll
    for (int i = 0; i < 4; ++i)
      #pragma unroll
      for (int j = 0; j < 4; ++j)
        acc[i][j] = __builtin_amdgcn_mfma_f32_16x16x32_bf16(
            __builtin_bit_cast(bf16x8, af[i]), __builtin_bit_cast(bf16x8, bfr[j]),
            acc[i][j], 0, 0, 0);
  }

  const int mode = bx >> 2;   // 0=q, 1=k, 2=v (block-uniform)
  if (mode == 0) {
    #pragma unroll
    for (int j = 0; j < 4; ++j) {
      int col = n0 + nw + j * 16 + l15;
      float bv = gread(bias, wf, col);
      #pragma unroll
      for (int i = 0; i < 4; ++i)
        #pragma unroll
        for (int r = 0; r < 4; ++r) {
          int row = m0 + mw + i * 16 + quad * 4 + r;
          qb[(size_t)row * 512 + col] = f2bf(acc[i][j][r] + bv);
        }
    }
  } else {
    unsigned short* dstbuf = (mode == 1) ? ekg : vmg;
    float bj[4]; int hj[4], dj[4];
    #pragma unroll
    for (int j = 0; j < 4; ++j) {
      int col = n0 + nw + j * 16 + l15;
      bj[j] = gread(bias, wf, col);
      int rel = col - mode * 512;
      hj[j] = rel >> 6; dj[j] = rel & 63;
    }
    #pragma unroll
    for (int i = 0; i < 4; ++i)
      #pragma unroll
      for (int r = 0; r < 4; ++r) {
        int row = m0 + mw + i * 16 + quad * 4 + r;
        bool mk = mask_at(mask, mf, row);
        int bb2 = row >> 12, nn = row & 4095;
        size_t base = (size_t)(nn >> 3) * 512 + (nn & 7);
        #pragma unroll
        for (int j = 0; j < 4; ++j) {
          float val = acc[i][j][r] + bj[j];
          val = (mode == 1) ? (mk ? __expf(val) : 0.f) : (mk ? val : 0.f);
          dstbuf[(size_t)(bb2 * 8 + hj[j]) * 262144 + base + (size_t)dj[j] * 8] = f2bf(val);
        }
      }
  }
}

// ---------------- kv GEMM: per-block partial over 256 tokens, 512 blocks ----------
__global__ __launch_bounds__(256)
void kv_gemm(const unsigned short* __restrict__ ekg,
             const unsigned short* __restrict__ vmg,
             float* __restrict__ kvpart, float* __restrict__ denpart)
{
  const int sc = blockIdx.x;   // 0..15 (256-token chunk)
  const int bh = blockIdx.y;   // 0..31
  const int t  = threadIdx.x;
  const int lane = t & 63, wv = t >> 6;
  const int quad = lane >> 4, l15 = lane & 15;
  __shared__ alignas(16) unsigned short ekS[16384];  // [ktl 0..31][d 0..63][8]
  __shared__ alignas(16) unsigned short vmS[16384];

  f32x4 acc[4];
  #pragma unroll
  for (int j = 0; j < 4; ++j) acc[j] = (f32x4){0.f,0.f,0.f,0.f};
  float dsum = 0.f;
  const int dden = t & 63, g0 = (t >> 6) * 8;
  const size_t gbase = (size_t)bh * 262144 + (size_t)sc * 16384;

  #pragma unroll
  for (int i = 0; i < 8; ++i) {
    int u0 = i * 256 + wv * 64;          // wave-uniform LDS base, lane-contig global
    gld_lds16(&ekg[gbase + (size_t)(u0 + lane) * 8], &ekS[u0 * 8]);
    gld_lds16(&vmg[gbase + (size_t)(u0 + lane) * 8], &vmS[u0 * 8]);
  }
  __syncthreads();
  {  // denom partial: sum ek over staged tokens, per d
    #pragma unroll
    for (int kt = 0; kt < 8; ++kt) {
      ushort8 v = *(const ushort8*)&ekS[((g0 + kt) * 64 + dden) * 8];
      #pragma unroll
      for (int j = 0; j < 8; ++j) dsum += bf2f(v[j]);
    }
  }
  #pragma unroll 2
  for (int ks = 0; ks < 8; ++ks) {
    ushort8 af = *(const ushort8*)&ekS[((ks * 4 + quad) * 64 + wv * 16 + l15) * 8];
    #pragma unroll
    for (int jt = 0; jt < 4; ++jt) {
      ushort8 bf8 = *(const ushort8*)&vmS[((ks * 4 + quad) * 64 + jt * 16 + l15) * 8];
      acc[jt] = __builtin_amdgcn_mfma_f32_16x16x32_bf16(
          __builtin_bit_cast(bf16x8, af), __builtin_bit_cast(bf16x8, bf8),
          acc[jt], 0, 0, 0);
    }
  }
  float* kvp = kvpart + (size_t)(sc * 32 + bh) * 4096;
  #pragma unroll
  for (int jt = 0; jt < 4; ++jt)
    #pragma unroll
    for (int r = 0; r < 4; ++r)
      kvp[(wv * 16 + quad * 4 + r) * 64 + jt * 16 + l15] = acc[jt][r];
  __syncthreads();
  float* red = (float*)ekS;
  red[t] = dsum;
  __syncthreads();
  if (t < 64)
    denpart[(sc * 32 + bh) * 64 + t] = red[t] + red[t + 64] + red[t + 128] + red[t + 192];
}

// ---------------- reduce partials -> normalized kv in bf16 B-frag layout ----------
// grid (32 bh, 4 d-quarters); kvnb[bh] unit (doct,e): kvn[doct*8+j][e] at ((doct*64+e)*8+j)
__global__ __launch_bounds__(256)
void kv_reduce(const float* __restrict__ kvpart, const float* __restrict__ denpart,
               unsigned short* __restrict__ kvnb)
{
  const int bh = blockIdx.x;     // 0..31
  const int qd = blockIdx.y;     // 0..3: d-range qd*16..+15
  const int t  = threadIdx.x;
  __shared__ float den[16];
  if (t < 16) {
    float s = 0.f;
    #pragma unroll
    for (int c = 0; c < 16; ++c) s += denpart[(c * 32 + bh) * 64 + qd * 16 + t];
    den[t] = s;
  }
  __syncthreads();
  const int dl = t >> 4, e0 = (t & 15) * 4;
  const int d = qd * 16 + dl;
  float sx = 0.f, sy = 0.f, sz = 0.f, sw = 0.f;
  #pragma unroll
  for (int c = 0; c < 16; ++c) {
    const float4 v = *(const float4*)&kvpart[(size_t)(c * 32 + bh) * 4096 + d * 64 + e0];
    sx += v.x; sy += v.y; sz += v.z; sw += v.w;
  }
  const float inv = 1.f / den[dl];
  const float sv[4] = {sx, sy, sz, sw};
  #pragma unroll
  for (int j = 0; j < 4; ++j) {
    int e = e0 + j;
    kvnb[(size_t)bh * 4096 + ((size_t)(d >> 3) * 64 + e) * 8 + (d & 7)] = f2bf(sv[j] * inv);
  }
}

// ---------------- output: in-register q-softmax in MFMA A-frag layout -------------
__global__ __launch_bounds__(256)
void out_pass(const unsigned short* __restrict__ qb,
              const unsigned short* __restrict__ kvnb,
              float* __restrict__ out)
{
  const int chunk = blockIdx.x, bh = blockIdx.y;
  const int b = bh >> 3, h = bh & 7;
  const int t = threadIdx.x;
  const int lane = t & 63, wv = t >> 6;
  const int quad = lane >> 4, l15 = lane & 15;
  __shared__ alignas(16) unsigned short kvS[4096];   // [(doct*64+e)*8+j]
  #pragma unroll
  for (int i = 0; i < 2; ++i)
    *(ushort8*)&kvS[(t + i * 256) * 8] =
        *(const ushort8*)&kvnb[(size_t)bh * 4096 + (size_t)(t + i * 256) * 8];
  __syncthreads();

  for (int g = 0; g < 4; ++g) {
    const int tok0 = chunk * 256 + wv * 64 + g * 16;
    const size_t qoff = (size_t)(b * N_ + tok0 + l15) * 512 + h * DH_ + quad * 8;
    uint4 qa = *(const uint4*)(qb + qoff);        // d = quad*8 .. +7
    uint4 qc = *(const uint4*)(qb + qoff + 32);   // d = 32+quad*8 .. +7
    float qf[16];
    unpack8(qa, qf); unpack8(qc, qf + 8);
    float mx = qf[0];
    #pragma unroll
    for (int jj = 1; jj < 16; ++jj) mx = fmaxf(mx, qf[jj]);
    mx = fmaxf(mx, __shfl_xor(mx, 16));
    mx = fmaxf(mx, __shfl_xor(mx, 32));
    float s = 0.f;
    #pragma unroll
    for (int jj = 0; jj < 16; ++jj) { qf[jj] = __expf(qf[jj] - mx); s += qf[jj]; }
    s += __shfl_xor(s, 16);
    s += __shfl_xor(s, 32);
    const float inv = 1.f / s;
    ushort8 af0, af1;
    #pragma unroll
    for (int jj = 0; jj < 8; ++jj) {
      af0[jj] = f2bf(qf[jj] * inv);
      af1[jj] = f2bf(qf[8 + jj] * inv);
    }
    f32x4 oa[4];
    #pragma unroll
    for (int jt = 0; jt < 4; ++jt) oa[jt] = (f32x4){0.f,0.f,0.f,0.f};
    #pragma unroll
    for (int jt = 0; jt < 4; ++jt) {
      ushort8 b0 = *(const ushort8*)&kvS[((0 + quad) * 64 + jt * 16 + l15) * 8];
      ushort8 b1 = *(const ushort8*)&kvS[((4 + quad) * 64 + jt * 16 + l15) * 8];
      oa[jt] = __builtin_amdgcn_mfma_f32_16x16x32_bf16(
          __builtin_bit_cast(bf16x8, af0), __builtin_bit_cast(bf16x8, b0), oa[jt], 0, 0, 0);
      oa[jt] = __builtin_amdgcn_mfma_f32_16x16x32_bf16(
          __builtin_bit_cast(bf16x8, af1), __builtin_bit_cast(bf16x8, b1), oa[jt], 0, 0, 0);
    }
    const size_t ob = (size_t)(b * N_ + tok0 + quad * 4) * 512 + h * DH_;
    #pragma unroll
    for (int jt = 0; jt < 4; ++jt)
      #pragma unroll
      for (int r = 0; r < 4; ++r)
        out[ob + (size_t)r * 512 + jt * 16 + l15] = oa[jt][r];
  }
}

// ================= round-5 fused fallback (only if ws too small) =================
__device__ inline void stage_x_f(float (*xa)[516], const void* x, int xf, int brow0, int t)
{
  if (xf) {
    const float* xp = (const float*)x;
    #pragma unroll
    for (int s = 0; s < 8; ++s) {
      int row = (t >> 7) + 2 * s, col = (t & 127) * 4;
      *(float4*)&xa[row][col] = *(const float4*)(xp + ((size_t)(brow0 + row)) * DIM_ + col);
    }
  } else {
    const unsigned short* xp = (const unsigned short*)x;
    #pragma unroll
    for (int s = 0; s < 8; ++s) {
      int row = (t >> 7) + 2 * s, col = (t & 127) * 4;
      const unsigned short* pp = xp + ((size_t)(brow0 + row)) * DIM_ + col;
      #pragma unroll
      for (int j = 0; j < 4; ++j) xa[row][col + j] = bf2f(pp[j]);
    }
  }
}

__global__ __launch_bounds__(256)
void kv_pass_fused(const void* __restrict__ x, const void* __restrict__ w,
                   const void* __restrict__ bias, const void* __restrict__ mask,
                   const int* __restrict__ flags,
                   float* __restrict__ kvbuf, float* __restrict__ denom)
{
  const int chunk = blockIdx.x, bh = blockIdx.y;
  const int b = bh >> 3, h = bh & 7;
  const int t = threadIdx.x;
  const int xf = flags[0], wf = flags[1], mf = flags[2];
  __shared__ float xa[16][516];
  __shared__ float Wb[64][130];
  float* ekb = &Wb[0][0];
  float* vvb = &Wb[0][0] + 16 * 65;
  const int tok = t >> 4, d0 = (t & 15) * 4;
  const int down = t >> 2, e0 = (t & 3) * 16;
  float acc[16];
  #pragma unroll
  for (int i = 0; i < 16; ++i) acc[i] = 0.f;
  float dsum = 0.f;
  for (int g = 0; g < 16; ++g) {
    const int n0 = chunk * 256 + g * 16;
    __syncthreads();
    stage_x_f(xa, x, xf, b * N_ + n0, t);
    float kreg[4] = {0,0,0,0}, vreg[4] = {0,0,0,0};
    for (int cc = 0; cc < 8; ++cc) {
      __syncthreads();
      {
        int c0 = (t >> 7) * 32, col = t & 127;
        int wc = (col < 64) ? (512 + h * DH_ + col) : (1024 + h * DH_ + (col - 64));
        #pragma unroll 8
        for (int j = 0; j < 32; ++j)
          Wb[c0 + j][col] = gread(w, wf, (size_t)(cc * 64 + c0 + j) * E3_ + wc);
      }
      __syncthreads();
      #pragma unroll 4
      for (int c = 0; c < 64; ++c) {
        float xv = xa[tok][cc * 64 + c];
        #pragma unroll
        for (int j = 0; j < 4; ++j) {
          kreg[j] += xv * Wb[c][d0 + j];
          vreg[j] += xv * Wb[c][64 + d0 + j];
        }
      }
    }
    bool mk = mask_at(mask, mf, b * N_ + n0 + tok);
    __syncthreads();
    #pragma unroll
    for (int j = 0; j < 4; ++j) {
      float kvl = kreg[j] + gread(bias, wf, 512  + h * DH_ + d0 + j);
      float vvl = vreg[j] + gread(bias, wf, 1024 + h * DH_ + d0 + j);
      ekb[tok * 65 + d0 + j] = mk ? __expf(kvl) : 0.f;
      vvb[tok * 65 + d0 + j] = mk ? vvl : 0.f;
    }
    __syncthreads();
    #pragma unroll 4
    for (int nn = 0; nn < 16; ++nn) {
      float ekd = ekb[nn * 65 + down];
      if (e0 == 0) dsum += ekd;
      #pragma unroll
      for (int i = 0; i < 16; ++i) acc[i] += ekd * vvb[nn * 65 + e0 + i];
    }
  }
  float* kvp = kvbuf + (size_t)bh * 4096 + down * 64 + e0;
  #pragma unroll
  for (int i = 0; i < 16; ++i) atomicAdd(&kvp[i], acc[i]);
  if (e0 == 0) atomicAdd(&denom[bh * 64 + down], dsum);
}

__global__ __launch_bounds__(256)
void out_pass_fused(const void* __restrict__ x, const void* __restrict__ w,
                    const void* __restrict__ bias, const int* __restrict__ flags,
                    const float* __restrict__ kvbuf, const float* __restrict__ denom,
                    float* __restrict__ out)
{
  const int chunk = blockIdx.x, bh = blockIdx.y;
  const int b = bh >> 3, h = bh & 7;
  const int t = threadIdx.x;
  const int xf = flags[0], wf = flags[1];
  __shared__ float xa[16][516];
  __shared__ float Wq[64][66];
  __shared__ float kvn[64][68];
  float* qsm = &Wq[0][0];
  for (int i = t; i < 4096; i += 256) {
    int d = i >> 6, e = i & 63;
    kvn[d][e] = kvbuf[(size_t)bh * 4096 + i] / denom[bh * 64 + d];
  }
  const int tok = t >> 4, p = t & 15, d0 = p * 4;
  for (int g = 0; g < 16; ++g) {
    const int n0 = chunk * 256 + g * 16;
    __syncthreads();
    stage_x_f(xa, x, xf, b * N_ + n0, t);
    float qreg[4] = {0,0,0,0};
    for (int cc = 0; cc < 8; ++cc) {
      __syncthreads();
      {
        int col = t & 63, c0 = (t >> 6) * 16;
        #pragma unroll 8
        for (int j = 0; j < 16; ++j)
          Wq[c0 + j][col] = gread(w, wf, (size_t)(cc * 64 + c0 + j) * E3_ + h * DH_ + col);
      }
      __syncthreads();
      #pragma unroll 4
      for (int c = 0; c < 64; ++c) {
        float xv = xa[tok][cc * 64 + c];
        #pragma unroll
        for (int j = 0; j < 4; ++j) qreg[j] += xv * Wq[c][d0 + j];
      }
    }
    #pragma unroll
    for (int j = 0; j < 4; ++j) qreg[j] += gread(bias, wf, h * DH_ + d0 + j);
    float mx = fmaxf(fmaxf(qreg[0], qreg[1]), fmaxf(qreg[2], qreg[3]));
    #pragma unroll
    for (int o = 1; o < 16; o <<= 1) mx = fmaxf(mx, __shfl_xor(mx, o, 16));
    float s = 0.f;
    #pragma unroll
    for (int j = 0; j < 4; ++j) { qreg[j] = __expf(qreg[j] - mx); s += qreg[j]; }
    #pragma unroll
    for (int o = 1; o < 16; o <<= 1) s += __shfl_xor(s, o, 16);
    float inv = 1.f / s;
    __syncthreads();
    #pragma unroll
    for (int j = 0; j < 4; ++j) qsm[tok * 65 + d0 + j] = qreg[j] * inv;
    __syncthreads();
    {
      int e0 = p * 4;
      float ov[4] = {0,0,0,0};
      #pragma unroll 4
      for (int d = 0; d < 64; ++d) {
        float qd = qsm[tok * 65 + d];
        #pragma unroll
        for (int j = 0; j < 4; ++j) ov[j] += qd * kvn[d][e0 + j];
      }
      size_t ob = ((size_t)(b * N_ + n0 + tok)) * DIM_ + h * DH_ + e0;
      #pragma unroll
      for (int j = 0; j < 4; ++j) out[ob + j] = ov[j];
    }
  }
}

extern "C" void kernel_launch(void* const* d_in, const int* in_sizes, int n_in,
                              void* d_out, int out_size, void* d_ws, size_t ws_size,
                              hipStream_t stream)
{
  const void* x    = d_in[0];
  const void* mask = d_in[1];
  const void* w    = d_in[2];
  const void* bias = d_in[3];
  float* out = (float*)d_out;

  char* ws = (char*)d_ws;
  const size_t offFlg = 0;                                   // 4 KB slot
  const size_t offXq  = 4096;                                // 16.78 MB (dead after GEMM)
  const size_t offWq  = offXq + (size_t)M_ * DIM_ * 2;       // 1.57 MB
  const size_t offQ   = offWq + (size_t)E3_ * DIM_ * 2;      // 16.78 MB
  const size_t offEk  = offQ  + (size_t)M_ * DIM_ * 2;       // 16.78 MB
  const size_t offVm  = offEk + (size_t)M_ * DH_ * H_ * 2;   // 16.78 MB
  const size_t need   = offVm + (size_t)M_ * DH_ * H_ * 2;
  // aliased into dead xq region (after qkv_gemm_fused):
  const size_t offKvp = offXq;                               // 16*32*4096*4 = 8 MB
  const size_t offDnp = offXq + 8388608;                     // 16*32*64*4 = 128 KB
  const size_t offKvn = offXq + 8388608 + 131072;            // 256 KB

  int* flags = (int*)(ws + offFlg);
  detect_fmt<<<1, 256, 0, stream>>>((const unsigned int*)x, (const unsigned int*)w,
                                    (const unsigned int*)mask, flags);

  if (ws_size >= need) {
    unsigned short* xq  = (unsigned short*)(ws + offXq);
    unsigned short* wq  = (unsigned short*)(ws + offWq);
    unsigned short* qb  = (unsigned short*)(ws + offQ);
    unsigned short* ekg = (unsigned short*)(ws + offEk);
    unsigned short* vmg = (unsigned short*)(ws + offVm);
    float* kvpart = (float*)(ws + offKvp);
    float* denpart = (float*)(ws + offDnp);
    unsigned short* kvnb = (unsigned short*)(ws + offKvn);

    pack_xw<<<4480, 256, 0, stream>>>(x, w, xq, wq, flags);
    dim3 gg(E3_ / 128, M_ / 128);   // 12 x 128
    qkv_gemm_fused<<<gg, 256, 0, stream>>>(xq, wq, bias, mask, flags, qb, ekg, vmg);
    kv_gemm<<<dim3(16, 32), 256, 0, stream>>>(ekg, vmg, kvpart, denpart);
    kv_reduce<<<dim3(32, 4), 256, 0, stream>>>(kvpart, denpart, kvnb);
    out_pass<<<dim3(16, 32), 256, 0, stream>>>(qb, kvnb, out);
  } else {
    float* kvbuf = (float*)(ws + 4096);
    float* denom = (float*)(ws + 4096 + 32 * 4096 * 4);
    hipMemsetAsync(kvbuf, 0, 32 * 4096 * 4 + 32 * 64 * 4, stream);
    dim3 ga(16, 32);
    kv_pass_fused <<<ga, 256, 0, stream>>>(x, w, bias, mask, flags, kvbuf, denom);
    out_pass_fused<<<ga, 256, 0, stream>>>(x, w, bias, flags, kvbuf, denom, out);
  }
}